// Round 1
// baseline (311.764 us; speedup 1.0000x reference)
//
#include <hip/hip_runtime.h>

#define HIDDEN 128
#define NEDGES 800000
#define TILE_M 32
#define KDIM 384
#define NKSTEP 12   // 384 / 32

typedef __attribute__((ext_vector_type(8))) short short8;
typedef __attribute__((ext_vector_type(4))) float f32x4;

// f32 -> bf16 round-to-nearest-even
__device__ __forceinline__ unsigned short f2bf(float x) {
    union { float f; unsigned int u; } v; v.f = x;
    unsigned int u = v.u;
    u += 0x7fffu + ((u >> 16) & 1u);
    return (unsigned short)(u >> 16);
}

// Pack W (384x128 f32, rows = [W_src; W_dst; W_dist]) into bf16 MFMA
// B-fragment order: frag = ks*8 + nf; lane holds col n = nf*16 + (lane&15),
// k = ks*32 + (lane>>4)*8 + i, i=0..7, stored contiguously (16B per lane).
__global__ void __launch_bounds__(256) pack_w_kernel(const float* __restrict__ W,
                                                     unsigned short* __restrict__ Wp) {
    int t = blockIdx.x * 256 + threadIdx.x;
    if (t >= 96 * 64) return;
    int lane = t & 63;
    int frag = t >> 6;          // 0..95
    int ks = frag >> 3, nf = frag & 7;
    int hi = lane >> 4, lo = lane & 15;
    short8 g;
#pragma unroll
    for (int i = 0; i < 8; ++i) {
        int k = ks * 32 + hi * 8 + i;
        int n = nf * 16 + lo;
        g[i] = (short)f2bf(W[k * HIDDEN + n]);
    }
    *(short8*)(Wp + (size_t)t * 8) = g;
}

// stage 8 f32 (two float4) -> 8 bf16 into LDS row, XOR-swizzled granule
__device__ __forceinline__ void stage8(unsigned short* ldsrow, int col8, int swz,
                                       const float4* rowp, int g) {
    float4 u = rowp[2 * g];
    float4 v = rowp[2 * g + 1];
    short8 pk;
    pk[0] = (short)f2bf(u.x); pk[1] = (short)f2bf(u.y);
    pk[2] = (short)f2bf(u.z); pk[3] = (short)f2bf(u.w);
    pk[4] = (short)f2bf(v.x); pk[5] = (short)f2bf(v.y);
    pk[6] = (short)f2bf(v.z); pk[7] = (short)f2bf(v.w);
    *(short8*)(ldsrow + (size_t)(col8 ^ swz) * 8) = pk;
}

__global__ void __launch_bounds__(256) edge_gemm_kernel(
    const float* __restrict__ nef,     // 850000 x 128
    const float* __restrict__ dist,    // 800000 x 128
    const int*   __restrict__ srcs,
    const int*   __restrict__ dsts,
    const unsigned short* __restrict__ Wp,  // packed bf16 B fragments
    const float* __restrict__ bias,    // 128
    float*       __restrict__ out)     // 800000 x 128
{
    __shared__ __align__(16) unsigned short A_lds[TILE_M * KDIM]; // 24 KiB

    const int tid  = threadIdx.x;
    const int lane = tid & 63;
    const int wid  = tid >> 6;     // 0..3, wave owns cols [wid*32, wid*32+32)
    const int lo   = lane & 15;
    const int hi   = lane >> 4;

    // B fragments resident in registers for the whole kernel (96 VGPRs)
    short8 bfrag[NKSTEP][2];
#pragma unroll
    for (int ks = 0; ks < NKSTEP; ++ks) {
#pragma unroll
        for (int nf = 0; nf < 2; ++nf) {
            int frag = ks * 8 + wid * 2 + nf;
            bfrag[ks][nf] = *(const short8*)(Wp + ((size_t)frag * 64 + lane) * 8);
        }
    }

    const float bv0 = bias[wid * 32 + lo];
    const float bv1 = bias[wid * 32 + 16 + lo];

    const int eg  = tid >> 3;  // edge row in tile, 0..31
    const int lt  = tid & 7;   // 8 threads per edge
    const int swz = eg & 7;

    const int ntiles = NEDGES / TILE_M;  // 25000 exactly
    for (int tile = blockIdx.x; tile < ntiles; tile += gridDim.x) {
        // ---- stage: gather 3 x 128 f32 per edge -> bf16 LDS ----
        const int e = tile * TILE_M + eg;
        const int s = srcs[e];
        const int d = dsts[e];
        const float4* srow = (const float4*)nef  + (size_t)s * 32;
        const float4* drow = (const float4*)nef  + (size_t)d * 32;
        const float4* frow = (const float4*)dist + (size_t)e * 32;
        unsigned short* ldsrow = A_lds + eg * KDIM;
#pragma unroll
        for (int j = 0; j < 2; ++j) {
            int g = lt + 8 * j;                 // granule in segment, 0..15
            stage8(ldsrow,      g, swz, srow, g);  // k 0..127   (src)
            stage8(ldsrow, 16 + g, swz, drow, g);  // k 128..255 (dst)
            stage8(ldsrow, 32 + g, swz, frow, g);  // k 256..383 (dist)
        }
        __syncthreads();

        // ---- compute: 12 K-steps x (2 M-frags x 2 N-frags) MFMA ----
        f32x4 acc00 = {0.f, 0.f, 0.f, 0.f};
        f32x4 acc01 = {0.f, 0.f, 0.f, 0.f};
        f32x4 acc10 = {0.f, 0.f, 0.f, 0.f};
        f32x4 acc11 = {0.f, 0.f, 0.f, 0.f};
#pragma unroll
        for (int ks = 0; ks < NKSTEP; ++ks) {
            const int row0 = lo;
            const int row1 = 16 + lo;
            const int c8   = ks * 4 + hi;
            short8 a0 = *(const short8*)(A_lds + row0 * KDIM + ((c8 ^ (row0 & 7)) * 8));
            short8 a1 = *(const short8*)(A_lds + row1 * KDIM + ((c8 ^ (row1 & 7)) * 8));
            acc00 = __builtin_amdgcn_mfma_f32_16x16x32_bf16(a0, bfrag[ks][0], acc00, 0, 0, 0);
            acc01 = __builtin_amdgcn_mfma_f32_16x16x32_bf16(a0, bfrag[ks][1], acc01, 0, 0, 0);
            acc10 = __builtin_amdgcn_mfma_f32_16x16x32_bf16(a1, bfrag[ks][0], acc10, 0, 0, 0);
            acc11 = __builtin_amdgcn_mfma_f32_16x16x32_bf16(a1, bfrag[ks][1], acc11, 0, 0, 0);
        }
        __syncthreads();

        // ---- epilogue: +bias, relu, store f32 ----
        // C/D layout (m89-verified): col = lane&15, row = (lane>>4)*4 + r
#pragma unroll
        for (int r = 0; r < 4; ++r) {
            const int row0 = tile * TILE_M + hi * 4 + r;
            const int row1 = row0 + 16;
            const int col0 = wid * 32 + lo;
            const int col1 = col0 + 16;
            float v00 = acc00[r] + bv0;
            float v01 = acc01[r] + bv1;
            float v10 = acc10[r] + bv0;
            float v11 = acc11[r] + bv1;
            out[(size_t)row0 * HIDDEN + col0] = v00 > 0.f ? v00 : 0.f;
            out[(size_t)row0 * HIDDEN + col1] = v01 > 0.f ? v01 : 0.f;
            out[(size_t)row1 * HIDDEN + col0] = v10 > 0.f ? v10 : 0.f;
            out[(size_t)row1 * HIDDEN + col1] = v11 > 0.f ? v11 : 0.f;
        }
    }
}

extern "C" void kernel_launch(void* const* d_in, const int* in_sizes, int n_in,
                              void* d_out, int out_size, void* d_ws, size_t ws_size,
                              hipStream_t stream) {
    const float* nef  = (const float*)d_in[0];
    const float* dist = (const float*)d_in[1];
    const int*   srcs = (const int*)d_in[2];
    const int*   dsts = (const int*)d_in[3];
    const float* W    = (const float*)d_in[4];
    const float* bias = (const float*)d_in[5];
    float* out = (float*)d_out;
    unsigned short* Wp = (unsigned short*)d_ws;  // 96 KiB packed bf16 W

    hipLaunchKernelGGL(pack_w_kernel, dim3(24), dim3(256), 0, stream, W, Wp);
    hipLaunchKernelGGL(edge_gemm_kernel, dim3(2048), dim3(256), 0, stream,
                       nef, dist, srcs, dsts, Wp, bias, out);
}